// Round 12
// baseline (69.379 us; speedup 1.0000x reference)
//
#include <hip/hip_runtime.h>
#include <hip/hip_bf16.h>

typedef short bf16x8 __attribute__((ext_vector_type(8)));
typedef float f32x4 __attribute__((ext_vector_type(4)));
typedef unsigned short u16;
typedef unsigned short u16x4 __attribute__((ext_vector_type(4)));
typedef unsigned short u16x8 __attribute__((ext_vector_type(8)));

#define FINF 1.0e12f

__device__ __forceinline__ u16 f2b(float f) {
  union { float f; unsigned int u; } x; x.f = f;
  unsigned int r = x.u + 0x7fffu + ((x.u >> 16) & 1u);
  return (u16)(r >> 16);
}

// Kernel 0: W1 (1024x128 f32) -> bf16 in MFMA B-fragment order.
__global__ __launch_bounds__(256) void k0_w1frag(const float* __restrict__ W1,
                                                 u16* __restrict__ w1f) {
  int idx = blockIdx.x * 256 + threadIdx.x;   // 0..131071
  int k = idx >> 7, c = idx & 127;
  float v = W1[idx];
  int chunk = k >> 6, kk = k & 63;
  int ks = kk >> 5, km = kk & 31, kg = km >> 3, i = km & 7;
  int nt = c >> 4, ln = c & 15;
  int dst = chunk * 8192 + (nt * 2 + ks) * 512 + (kg * 16 + ln) * 8 + i;
  w1f[dst] = f2b(v);
}

// Kernel 1: identical to round 11. Launched TWICE this round (idempotent) as
// a timing diagnostic: k1_dur = total - 55.9.
__global__ __launch_bounds__(256) void k1_prep(
    const float* __restrict__ inputs, const u16* __restrict__ w1f,
    const float* __restrict__ b1, const float* __restrict__ W2,
    const float* __restrict__ b2,
    u16* __restrict__ qw, u16* __restrict__ kw,
    float* __restrict__ biasE, float* __restrict__ biasO) {
  __shared__ __align__(16) char smem[49536];
  float* w2t = (float*)(smem + 36864);  // [c][k] pad 132
  float* xt  = (float*)smem;            // 16 x 132 f32 (alias, post-loop)

  int t = threadIdx.x;
  int lane = t & 63, w = t >> 6;        // 4 waves
  int r0 = blockIdx.x * 16;
  int b = r0 >> 9, l0 = r0 & 511;

  #pragma unroll
  for (int i = 0; i < 12; ++i) {
    int idx = t + i * 256;
    int k = idx / 24, c = idx - k * 24;
    w2t[c * 132 + k] = W2[idx];
  }

  f32x4 acc[2];
  acc[0] = (f32x4){0.f, 0.f, 0.f, 0.f};
  acc[1] = (f32x4){0.f, 0.f, 0.f, 0.f};

  int wnt = w * 2;

  int arow_s = t >> 4;                   // 0..15
  int aseg = t & 15;
  const float* ain = &inputs[(size_t)(r0 + arow_s) * 1024 + aseg * 4];
  int abyt = (arow_s * 128 + aseg * 8) ^ ((arow_s & 7) << 4);
  const float4* wsrcAll = (const float4*)w1f;

  float4 a0 = *(const float4*)(ain);
  float4 wr0 = wsrcAll[t];
  float4 wr1 = wsrcAll[t + 256];
  float4 wr2 = wsrcAll[t + 512];
  float4 wr3 = wsrcAll[t + 768];
  {
    u16x4 av;
    av[0] = f2b(a0.x); av[1] = f2b(a0.y); av[2] = f2b(a0.z); av[3] = f2b(a0.w);
    *(u16x4*)(smem + abyt) = av;
    float4* wd = (float4*)(smem + 4096);
    wd[t] = wr0; wd[t + 256] = wr1; wd[t + 512] = wr2; wd[t + 768] = wr3;
  }
  __syncthreads();

  for (int ch = 0; ch < 16; ++ch) {
    if (ch < 15) {
      a0 = *(const float4*)(ain + (ch + 1) * 64);
      const float4* wsrc = wsrcAll + (ch + 1) * 1024;
      wr0 = wsrc[t]; wr1 = wsrc[t + 256]; wr2 = wsrc[t + 512]; wr3 = wsrc[t + 768];
    }
    {
      const char* Ab = smem + (ch & 1) * 2048;
      const u16* Wb = (const u16*)(smem + 4096 + (ch & 1) * 16384);
      int arow = lane & 15;
      int hi = lane >> 4;
      #pragma unroll
      for (int ks = 0; ks < 2; ++ks) {
        int cb = ks * 64 + hi * 16;
        bf16x8 a = *(const bf16x8*)(Ab + ((arow * 128 + cb) ^ ((arow & 7) << 4)));
        #pragma unroll
        for (int nti = 0; nti < 2; ++nti) {
          int nt = wnt + nti;
          bf16x8 bb = *(const bf16x8*)&Wb[((nt * 2 + ks) * 64 + lane) * 8];
          acc[nti] = __builtin_amdgcn_mfma_f32_16x16x32_bf16(a, bb, acc[nti], 0, 0, 0);
        }
      }
    }
    if (ch < 15) {
      int q = (ch + 1) & 1;
      u16x4 av;
      av[0] = f2b(a0.x); av[1] = f2b(a0.y); av[2] = f2b(a0.z); av[3] = f2b(a0.w);
      *(u16x4*)(smem + q * 2048 + abyt) = av;
      float4* wd = (float4*)(smem + 4096 + q * 16384);
      wd[t] = wr0; wd[t + 256] = wr1; wd[t + 512] = wr2; wd[t + 768] = wr3;
    }
    __syncthreads();
  }
  __syncthreads();

  #pragma unroll
  for (int nti = 0; nti < 2; ++nti) {
    int c = (wnt + nti) * 16 + (lane & 15);
    float b1v = b1[c];
    #pragma unroll
    for (int r = 0; r < 4; ++r) {
      int row = ((lane >> 4) << 2) + r;
      xt[row * 132 + c] = acc[nti][r] + b1v;
    }
  }
  __syncthreads();

  {
    int r = t >> 4, jb = (t & 15) * 2;
    int l = l0 + r;
    float fl = (float)l;
    u16x4 qv, kv;
    #pragma unroll
    for (int p = 0; p < 2; ++p) {
      int j = jb + p;
      float4 x4 = *(const float4*)&xt[r * 132 + 4 * j];
      float invf = exp2f(-0.4152410118609203f * (float)j);  // 10000^(-j/32)
      float ang = fl * invf;
      float rev = ang * 0.15915494309189535f;
      rev = rev - floorf(rev);
      float sv, cv;
      __sincosf(rev * 6.2831853071795864f, &sv, &cv);
      qv[2 * p] = f2b(x4.x * cv - x4.z * sv);
      qv[2 * p + 1] = f2b(x4.x * sv + x4.z * cv);
      kv[2 * p] = f2b(x4.y * cv - x4.w * sv);
      kv[2 * p + 1] = f2b(x4.y * sv + x4.w * cv);
    }
    size_t base = ((size_t)(b * 512 + l)) * 64 + jb * 2;
    *(u16x4*)&qw[base] = qv;
    *(u16x4*)&kw[base] = kv;
  }

  if (t < 192) {
    int c = t >> 3;
    int rg = (t & 7) * 2;
    float s0 = b2[c], s1 = s0;
    #pragma unroll
    for (int k4 = 0; k4 < 32; ++k4) {
      float4 wv = *(const float4*)&w2t[c * 132 + k4 * 4];
      float4 x0 = *(const float4*)&xt[(rg + 0) * 132 + k4 * 4];
      float4 x1 = *(const float4*)&xt[(rg + 1) * 132 + k4 * 4];
      s0 += x0.x * wv.x + x0.y * wv.y + x0.z * wv.z + x0.w * wv.w;
      s1 += x1.x * wv.x + x1.y * wv.y + x1.z * wv.z + x1.w * wv.w;
    }
    int h = c >> 1;
    size_t o = ((size_t)(b * 12 + h)) * 512 + l0 + rg;
    float2 sv = {s0 * 0.5f, s1 * 0.5f};
    if (c & 1) *(float2*)&biasO[o] = sv;
    else       *(float2*)&biasE[o] = sv;
  }
}

// Kernel 2: identical to round 11.
__global__ __launch_bounds__(256) void k2_main(
    const u16* __restrict__ qw, const u16* __restrict__ kw,
    const float* __restrict__ biasE, const float* __restrict__ biasO,
    const float* __restrict__ amask, float* __restrict__ out) {
  __shared__ char smem[24448];
  u16* Q = (u16*)smem;              // 8KB swizzled [m][d]
  u16* K = (u16*)(smem + 8192);     // 8KB swizzled [n][d]
  float* qkL = (float*)smem;        // 64x68 f32 (17408B) — overlaps Q/K (dead)
  float* BN = (float*)(smem + 17408);
  float* BM = (float*)(smem + 17408 + 3264);
  float* AMm = (float*)(smem + 17408 + 6528);
  float* AMn = AMm + 64;

  int t = threadIdx.x;
  int lane = t & 63, w = t >> 6;
  int n0 = blockIdx.x * 64, m0 = blockIdx.y * 64, b = blockIdx.z;
  bool skip = (m0 >= n0 + 64);  // fully below diagonal

  if (!skip) {
    int row = t >> 2, sg = t & 3;
    const u16x8* qsrc = (const u16x8*)&qw[((size_t)(b * 512 + m0 + row)) * 64 + sg * 16];
    u16x8 q0 = qsrc[0], q1 = qsrc[1];
    const u16x8* ksrc = (const u16x8*)&kw[((size_t)(b * 512 + n0 + row)) * 64 + sg * 16];
    u16x8 k0v = ksrc[0], k1v = ksrc[1];
    int swz = (row & 7) << 4;
    int byt = row * 128 + sg * 32;
    *(u16x8*)((char*)Q + ((byt) ^ swz)) = q0;
    *(u16x8*)((char*)Q + ((byt + 16) ^ swz)) = q1;
    *(u16x8*)((char*)K + ((byt) ^ swz)) = k0v;
    *(u16x8*)((char*)K + ((byt + 16) ^ swz)) = k1v;
  }
  if (t < 192) {
    int h = t >> 4, kq = t & 15;
    *(float4*)&BN[h * 68 + kq * 4] =
        *(const float4*)&biasE[((size_t)(b * 12 + h)) * 512 + n0 + kq * 4];
    *(float4*)&BM[h * 68 + kq * 4] =
        *(const float4*)&biasO[((size_t)(b * 12 + h)) * 512 + m0 + kq * 4];
  } else if (t < 224) {
    int i = t - 192;
    if (i < 16) *(float4*)&AMm[i * 4] = *(const float4*)&amask[b * 512 + m0 + i * 4];
    else { int ii = i - 16; *(float4*)&AMn[ii * 4] = *(const float4*)&amask[b * 512 + n0 + ii * 4]; }
  }
  __syncthreads();

  if (!skip) {
    f32x4 acc[4];
    #pragma unroll
    for (int nt = 0; nt < 4; ++nt) acc[nt] = (f32x4){0.f, 0.f, 0.f, 0.f};
    int mrow = w * 16 + (lane & 15);
    int hi = lane >> 4;
    #pragma unroll
    for (int ks = 0; ks < 2; ++ks) {
      int cb = ks * 64 + hi * 16;
      bf16x8 a = *(const bf16x8*)((const char*)Q +
                                  ((mrow * 128 + cb) ^ ((mrow & 7) << 4)));
      #pragma unroll
      for (int nt = 0; nt < 4; ++nt) {
        int nr = nt * 16 + (lane & 15);
        bf16x8 bb = *(const bf16x8*)((const char*)K +
                                     ((nr * 128 + cb) ^ ((nr & 7) << 4)));
        acc[nt] = __builtin_amdgcn_mfma_f32_16x16x32_bf16(a, bb, acc[nt], 0, 0, 0);
      }
    }
    __syncthreads();  // Q/K dead; safe to overwrite with qkL
    #pragma unroll
    for (int nt = 0; nt < 4; ++nt)
      #pragma unroll
      for (int r = 0; r < 4; ++r)
        qkL[(w * 16 + hi * 4 + r) * 68 + nt * 16 + (lane & 15)] = acc[nt][r];
    __syncthreads();
  }

  int a15 = t & 15, mb = t >> 4;  // thread owns n = 4*a15+j, m = mb+16*mi
  float amn0 = AMn[a15 * 4 + 0], amn1 = AMn[a15 * 4 + 1];
  float amn2 = AMn[a15 * 4 + 2], amn3 = AMn[a15 * 4 + 3];
  float vals[4][4];
  #pragma unroll
  for (int mi = 0; mi < 4; ++mi) {
    int m = mb + 16 * mi;
    int mg = m0 + m;
    float amm = AMm[m];
    int ng = n0 + a15 * 4;
    float p0 = (1.f - amm * amn0) * FINF + ((mg > ng + 0) ? FINF : 0.f);
    float p1 = (1.f - amm * amn1) * FINF + ((mg > ng + 1) ? FINF : 0.f);
    float p2 = (1.f - amm * amn2) * FINF + ((mg > ng + 2) ? FINF : 0.f);
    float p3 = (1.f - amm * amn3) * FINF + ((mg > ng + 3) ? FINF : 0.f);
    if (!skip) {
      float4 qk = *(const float4*)&qkL[m * 68 + a15 * 4];
      vals[mi][0] = qk.x * 0.125f - p0;
      vals[mi][1] = qk.y * 0.125f - p1;
      vals[mi][2] = qk.z * 0.125f - p2;
      vals[mi][3] = qk.w * 0.125f - p3;
    } else {
      vals[mi][0] = -p0; vals[mi][1] = -p1; vals[mi][2] = -p2; vals[mi][3] = -p3;
    }
  }

  size_t outbase = (size_t)(b * 12) * 262144 + (size_t)m0 * 512 + n0 + a15 * 4;
  #pragma unroll
  for (int h = 0; h < 12; ++h) {
    float4 bn = *(const float4*)&BN[h * 68 + a15 * 4];
    #pragma unroll
    for (int mi = 0; mi < 4; ++mi) {
      int m = mb + 16 * mi;
      float bm = BM[h * 68 + m];
      float4 v;
      v.x = vals[mi][0] + bn.x + bm;
      v.y = vals[mi][1] + bn.y + bm;
      v.z = vals[mi][2] + bn.z + bm;
      v.w = vals[mi][3] + bn.w + bm;
      *(float4*)&out[outbase + (size_t)h * 262144 + (size_t)m * 512] = v;
    }
  }
}

extern "C" void kernel_launch(void* const* d_in, const int* in_sizes, int n_in,
                              void* d_out, int out_size, void* d_ws, size_t ws_size,
                              hipStream_t stream) {
  const float* inputs = (const float*)d_in[0];
  const float* amask  = (const float*)d_in[1];
  const float* W1     = (const float*)d_in[2];
  const float* b1     = (const float*)d_in[3];
  const float* W2     = (const float*)d_in[4];
  const float* b2     = (const float*)d_in[5];
  float* out = (float*)d_out;

  char* ws = (char*)d_ws;
  u16* qw      = (u16*)(ws);                            // 1 MB
  u16* kw      = (u16*)(ws + (1u << 20));               // 1 MB
  float* biasE = (float*)(ws + (2u << 20));             // 384 KB
  float* biasO = (float*)(ws + (2u << 20) + 393216u);   // 384 KB
  u16* w1f     = (u16*)(ws + (2u << 20) + 786432u);     // 256 KB

  k0_w1frag<<<512, 256, 0, stream>>>(W1, w1f);
  k1_prep<<<512, 256, 0, stream>>>(inputs, w1f, b1, W2, b2, qw, kw, biasE, biasO);
  // DIAGNOSTIC: k1 launched twice (idempotent). k1_dur = total - 55.9.
  k1_prep<<<512, 256, 0, stream>>>(inputs, w1f, b1, W2, b2, qw, kw, biasE, biasO);
  k2_main<<<dim3(8, 8, 16), 256, 0, stream>>>(qw, kw, biasE, biasO, amask, out);
}

// Round 13
// 57.936 us; speedup vs baseline: 1.1975x; 1.1975x over previous
//
#include <hip/hip_runtime.h>
#include <hip/hip_bf16.h>

typedef short bf16x8 __attribute__((ext_vector_type(8)));
typedef float f32x4 __attribute__((ext_vector_type(4)));
typedef unsigned short u16;
typedef unsigned short u16x4 __attribute__((ext_vector_type(4)));
typedef unsigned short u16x8 __attribute__((ext_vector_type(8)));

#define FINF 1.0e12f

__device__ __forceinline__ u16 f2b(float f) {
  union { float f; unsigned int u; } x; x.f = f;
  unsigned int r = x.u + 0x7fffu + ((x.u >> 16) & 1u);
  return (u16)(r >> 16);
}

// Kernel 0 (inverted mapping): thread owns 8 CONSECUTIVE w1f elements
// (one coalesced 16B store), gathers 8 strided W1 reads.
// dst d: i=d&7, ln=(d>>3)&15, kg=(d>>7)&3, ksnt=(d>>9)&15, chunk=d>>13;
// k = chunk*64 + (ksnt&1)*32 + kg*8 + i ; c = (ksnt>>1)*16 + ln.
__global__ __launch_bounds__(256) void k0_w1frag(const float* __restrict__ W1,
                                                 u16* __restrict__ w1f) {
  int t8 = blockIdx.x * 256 + threadIdx.x;   // 0..16383
  int ln = t8 & 15;
  int kg = (t8 >> 4) & 3;
  int ksnt = (t8 >> 6) & 15;
  int chunk = t8 >> 10;
  int ks = ksnt & 1, nt = ksnt >> 1;
  int kbase = chunk * 64 + ks * 32 + kg * 8;
  int c = nt * 16 + ln;
  u16x8 v;
  #pragma unroll
  for (int i = 0; i < 8; ++i) v[i] = f2b(W1[(size_t)(kbase + i) * 128 + c]);
  *(u16x8*)&w1f[t8 * 8] = v;
}

// Kernel 1: 512 blocks x 16 rows, 256 threads (4 waves), 2 blocks/CU.
// A-tile staged ONCE in LDS (bf16, swizzled); W fragments stream
// global->register (2-deep dbuf, fully unrolled); K-loop is BARRIER-FREE.
// smem: A @0 (32KB) | w2t @32768 (12672B). xt (8448B) aliases @0 post-loop.
__global__ __launch_bounds__(256) void k1_prep(
    const float* __restrict__ inputs, const u16* __restrict__ w1f,
    const float* __restrict__ b1, const float* __restrict__ W2,
    const float* __restrict__ b2,
    u16* __restrict__ qw, u16* __restrict__ kw,
    float* __restrict__ biasE, float* __restrict__ biasO) {
  __shared__ __align__(16) char smem[45440];
  float* w2t = (float*)(smem + 32768);  // [c][k] pad 132
  float* xt  = (float*)smem;            // 16 x 132 f32 (alias, post-loop)

  int t = threadIdx.x;
  int lane = t & 63, w = t >> 6;        // 4 waves
  int r0 = blockIdx.x * 16;
  int b = r0 >> 9, l0 = r0 & 511;

  // stage W2^T (3072 elems)
  #pragma unroll
  for (int i = 0; i < 12; ++i) {
    int idx = t + i * 256;
    int k = idx / 24, c = idx - k * 24;
    w2t[c * 132 + k] = W2[idx];
  }

  // stage full A tile: 16 rows x 1024 cols -> bf16, swizzled rows (2048B)
  {
    int r = t >> 4, c4 = (t & 15) * 4;
    const float* src = &inputs[(size_t)(r0 + r) * 1024 + c4];
    int swz = (r & 7) << 4;
    int bbase = r * 2048 + c4 * 2;
    #pragma unroll
    for (int j = 0; j < 16; ++j) {
      float4 f = *(const float4*)(src + j * 64);
      u16x4 v4;
      v4[0] = f2b(f.x); v4[1] = f2b(f.y); v4[2] = f2b(f.z); v4[3] = f2b(f.w);
      *(u16x4*)(smem + ((bbase + j * 128) ^ swz)) = v4;
    }
  }
  __syncthreads();

  // ---- barrier-free K-loop ----
  f32x4 acc[2];
  acc[0] = (f32x4){0.f, 0.f, 0.f, 0.f};
  acc[1] = (f32x4){0.f, 0.f, 0.f, 0.f};
  int wnt = w * 2;
  int arow = lane & 15, hi = lane >> 4;
  int swzr = (arow & 7) << 4;
  int abase = arow * 2048 + hi * 16;
  const u16* wbase = w1f + lane * 8 + (size_t)wnt * 1024;  // (wnt*2)*512

  bf16x8 wf0[4], wf1[4];
  #pragma unroll
  for (int q = 0; q < 4; ++q)
    wf0[q] = *(const bf16x8*)(wbase + q * 512);
  #pragma unroll
  for (int ch = 0; ch < 16; ++ch) {
    if (ch < 15) {
      const u16* wc = wbase + (ch + 1) * 8192;
      if (ch & 1) {
        #pragma unroll
        for (int q = 0; q < 4; ++q) wf0[q] = *(const bf16x8*)(wc + q * 512);
      } else {
        #pragma unroll
        for (int q = 0; q < 4; ++q) wf1[q] = *(const bf16x8*)(wc + q * 512);
      }
    }
    #pragma unroll
    for (int ks = 0; ks < 2; ++ks) {
      bf16x8 a = *(const bf16x8*)(smem + ((abase + ch * 128 + ks * 64) ^ swzr));
      if (ch & 1) {
        acc[0] = __builtin_amdgcn_mfma_f32_16x16x32_bf16(a, wf1[ks], acc[0], 0, 0, 0);
        acc[1] = __builtin_amdgcn_mfma_f32_16x16x32_bf16(a, wf1[2 + ks], acc[1], 0, 0, 0);
      } else {
        acc[0] = __builtin_amdgcn_mfma_f32_16x16x32_bf16(a, wf0[ks], acc[0], 0, 0, 0);
        acc[1] = __builtin_amdgcn_mfma_f32_16x16x32_bf16(a, wf0[2 + ks], acc[1], 0, 0, 0);
      }
    }
  }
  __syncthreads();  // all waves' A reads done before xt aliases A

  // epilogue: acc -> xt (+ b1). D: col=lane&15, row=(lane>>4)*4+r
  #pragma unroll
  for (int nti = 0; nti < 2; ++nti) {
    int c = (wnt + nti) * 16 + (lane & 15);
    float b1v = b1[c];
    #pragma unroll
    for (int r = 0; r < 4; ++r) {
      int row = ((lane >> 4) << 2) + r;
      xt[row * 132 + c] = acc[nti][r] + b1v;
    }
  }
  __syncthreads();

  // RoPE: thread handles row t>>4, j = (t&15)*2 .. +1 ; outputs bf16
  {
    int r = t >> 4, jb = (t & 15) * 2;
    int l = l0 + r;
    float fl = (float)l;
    u16x4 qv, kv;
    #pragma unroll
    for (int p = 0; p < 2; ++p) {
      int j = jb + p;
      float4 x4 = *(const float4*)&xt[r * 132 + 4 * j];
      float invf = exp2f(-0.4152410118609203f * (float)j);  // 10000^(-j/32)
      float ang = fl * invf;
      float rev = ang * 0.15915494309189535f;
      rev = rev - floorf(rev);
      float sv, cv;
      __sincosf(rev * 6.2831853071795864f, &sv, &cv);
      qv[2 * p] = f2b(x4.x * cv - x4.z * sv);
      qv[2 * p + 1] = f2b(x4.x * sv + x4.z * cv);
      kv[2 * p] = f2b(x4.y * cv - x4.w * sv);
      kv[2 * p + 1] = f2b(x4.y * sv + x4.w * cv);
    }
    size_t base = ((size_t)(b * 512 + l)) * 64 + jb * 2;
    *(u16x4*)&qw[base] = qv;
    *(u16x4*)&kw[base] = kv;
  }

  // bias projection: (x @ W2 + b2)/2 ; thread (t<192): c = t>>3, rows (t&7)*2..+1
  if (t < 192) {
    int c = t >> 3;
    int rg = (t & 7) * 2;
    float s0 = b2[c], s1 = s0;
    #pragma unroll
    for (int k4 = 0; k4 < 32; ++k4) {
      float4 wv = *(const float4*)&w2t[c * 132 + k4 * 4];
      float4 x0 = *(const float4*)&xt[(rg + 0) * 132 + k4 * 4];
      float4 x1 = *(const float4*)&xt[(rg + 1) * 132 + k4 * 4];
      s0 += x0.x * wv.x + x0.y * wv.y + x0.z * wv.z + x0.w * wv.w;
      s1 += x1.x * wv.x + x1.y * wv.y + x1.z * wv.z + x1.w * wv.w;
    }
    int h = c >> 1;
    size_t o = ((size_t)(b * 12 + h)) * 512 + l0 + rg;
    float2 sv = {s0 * 0.5f, s1 * 0.5f};
    if (c & 1) *(float2*)&biasO[o] = sv;
    else       *(float2*)&biasE[o] = sv;
  }
}

// Kernel 2: identical to round 11 (measured ~32.3 us, ~store floor).
__global__ __launch_bounds__(256) void k2_main(
    const u16* __restrict__ qw, const u16* __restrict__ kw,
    const float* __restrict__ biasE, const float* __restrict__ biasO,
    const float* __restrict__ amask, float* __restrict__ out) {
  __shared__ char smem[24448];
  u16* Q = (u16*)smem;              // 8KB swizzled [m][d]
  u16* K = (u16*)(smem + 8192);     // 8KB swizzled [n][d]
  float* qkL = (float*)smem;        // 64x68 f32 (17408B) — overlaps Q/K (dead)
  float* BN = (float*)(smem + 17408);
  float* BM = (float*)(smem + 17408 + 3264);
  float* AMm = (float*)(smem + 17408 + 6528);
  float* AMn = AMm + 64;

  int t = threadIdx.x;
  int lane = t & 63, w = t >> 6;
  int n0 = blockIdx.x * 64, m0 = blockIdx.y * 64, b = blockIdx.z;
  bool skip = (m0 >= n0 + 64);  // fully below diagonal

  if (!skip) {
    int row = t >> 2, sg = t & 3;
    const u16x8* qsrc = (const u16x8*)&qw[((size_t)(b * 512 + m0 + row)) * 64 + sg * 16];
    u16x8 q0 = qsrc[0], q1 = qsrc[1];
    const u16x8* ksrc = (const u16x8*)&kw[((size_t)(b * 512 + n0 + row)) * 64 + sg * 16];
    u16x8 k0v = ksrc[0], k1v = ksrc[1];
    int swz = (row & 7) << 4;
    int byt = row * 128 + sg * 32;
    *(u16x8*)((char*)Q + ((byt) ^ swz)) = q0;
    *(u16x8*)((char*)Q + ((byt + 16) ^ swz)) = q1;
    *(u16x8*)((char*)K + ((byt) ^ swz)) = k0v;
    *(u16x8*)((char*)K + ((byt + 16) ^ swz)) = k1v;
  }
  if (t < 192) {
    int h = t >> 4, kq = t & 15;
    *(float4*)&BN[h * 68 + kq * 4] =
        *(const float4*)&biasE[((size_t)(b * 12 + h)) * 512 + n0 + kq * 4];
    *(float4*)&BM[h * 68 + kq * 4] =
        *(const float4*)&biasO[((size_t)(b * 12 + h)) * 512 + m0 + kq * 4];
  } else if (t < 224) {
    int i = t - 192;
    if (i < 16) *(float4*)&AMm[i * 4] = *(const float4*)&amask[b * 512 + m0 + i * 4];
    else { int ii = i - 16; *(float4*)&AMn[ii * 4] = *(const float4*)&amask[b * 512 + n0 + ii * 4]; }
  }
  __syncthreads();

  if (!skip) {
    f32x4 acc[4];
    #pragma unroll
    for (int nt = 0; nt < 4; ++nt) acc[nt] = (f32x4){0.f, 0.f, 0.f, 0.f};
    int mrow = w * 16 + (lane & 15);
    int hi = lane >> 4;
    #pragma unroll
    for (int ks = 0; ks < 2; ++ks) {
      int cb = ks * 64 + hi * 16;
      bf16x8 a = *(const bf16x8*)((const char*)Q +
                                  ((mrow * 128 + cb) ^ ((mrow & 7) << 4)));
      #pragma unroll
      for (int nt = 0; nt < 4; ++nt) {
        int nr = nt * 16 + (lane & 15);
        bf16x8 bb = *(const bf16x8*)((const char*)K +
                                     ((nr * 128 + cb) ^ ((nr & 7) << 4)));
        acc[nt] = __builtin_amdgcn_mfma_f32_16x16x32_bf16(a, bb, acc[nt], 0, 0, 0);
      }
    }
    __syncthreads();  // Q/K dead; safe to overwrite with qkL
    #pragma unroll
    for (int nt = 0; nt < 4; ++nt)
      #pragma unroll
      for (int r = 0; r < 4; ++r)
        qkL[(w * 16 + hi * 4 + r) * 68 + nt * 16 + (lane & 15)] = acc[nt][r];
    __syncthreads();
  }

  int a15 = t & 15, mb = t >> 4;  // thread owns n = 4*a15+j, m = mb+16*mi
  float amn0 = AMn[a15 * 4 + 0], amn1 = AMn[a15 * 4 + 1];
  float amn2 = AMn[a15 * 4 + 2], amn3 = AMn[a15 * 4 + 3];
  float vals[4][4];
  #pragma unroll
  for (int mi = 0; mi < 4; ++mi) {
    int m = mb + 16 * mi;
    int mg = m0 + m;
    float amm = AMm[m];
    int ng = n0 + a15 * 4;
    float p0 = (1.f - amm * amn0) * FINF + ((mg > ng + 0) ? FINF : 0.f);
    float p1 = (1.f - amm * amn1) * FINF + ((mg > ng + 1) ? FINF : 0.f);
    float p2 = (1.f - amm * amn2) * FINF + ((mg > ng + 2) ? FINF : 0.f);
    float p3 = (1.f - amm * amn3) * FINF + ((mg > ng + 3) ? FINF : 0.f);
    if (!skip) {
      float4 qk = *(const float4*)&qkL[m * 68 + a15 * 4];
      vals[mi][0] = qk.x * 0.125f - p0;
      vals[mi][1] = qk.y * 0.125f - p1;
      vals[mi][2] = qk.z * 0.125f - p2;
      vals[mi][3] = qk.w * 0.125f - p3;
    } else {
      vals[mi][0] = -p0; vals[mi][1] = -p1; vals[mi][2] = -p2; vals[mi][3] = -p3;
    }
  }

  size_t outbase = (size_t)(b * 12) * 262144 + (size_t)m0 * 512 + n0 + a15 * 4;
  #pragma unroll
  for (int h = 0; h < 12; ++h) {
    float4 bn = *(const float4*)&BN[h * 68 + a15 * 4];
    #pragma unroll
    for (int mi = 0; mi < 4; ++mi) {
      int m = mb + 16 * mi;
      float bm = BM[h * 68 + m];
      float4 v;
      v.x = vals[mi][0] + bn.x + bm;
      v.y = vals[mi][1] + bn.y + bm;
      v.z = vals[mi][2] + bn.z + bm;
      v.w = vals[mi][3] + bn.w + bm;
      *(float4*)&out[outbase + (size_t)h * 262144 + (size_t)m * 512] = v;
    }
  }
}

extern "C" void kernel_launch(void* const* d_in, const int* in_sizes, int n_in,
                              void* d_out, int out_size, void* d_ws, size_t ws_size,
                              hipStream_t stream) {
  const float* inputs = (const float*)d_in[0];
  const float* amask  = (const float*)d_in[1];
  const float* W1     = (const float*)d_in[2];
  const float* b1     = (const float*)d_in[3];
  const float* W2     = (const float*)d_in[4];
  const float* b2     = (const float*)d_in[5];
  float* out = (float*)d_out;

  char* ws = (char*)d_ws;
  u16* qw      = (u16*)(ws);                            // 1 MB
  u16* kw      = (u16*)(ws + (1u << 20));               // 1 MB
  float* biasE = (float*)(ws + (2u << 20));             // 384 KB
  float* biasO = (float*)(ws + (2u << 20) + 393216u);   // 384 KB
  u16* w1f     = (u16*)(ws + (2u << 20) + 786432u);     // 256 KB

  k0_w1frag<<<64, 256, 0, stream>>>(W1, w1f);
  k1_prep<<<512, 256, 0, stream>>>(inputs, w1f, b1, W2, b2, qw, kw, biasE, biasO);
  k2_main<<<dim3(8, 8, 16), 256, 0, stream>>>(qw, kw, biasE, biasO, amask, out);
}

// Round 14
// 57.157 us; speedup vs baseline: 1.2138x; 1.0136x over previous
//
#include <hip/hip_runtime.h>
#include <hip/hip_bf16.h>

typedef short bf16x8 __attribute__((ext_vector_type(8)));
typedef float f32x4 __attribute__((ext_vector_type(4)));
typedef unsigned short u16;
typedef unsigned short u16x4 __attribute__((ext_vector_type(4)));
typedef unsigned short u16x8 __attribute__((ext_vector_type(8)));

#define FINF 1.0e12f

__device__ __forceinline__ u16 f2b(float f) {
  union { float f; unsigned int u; } x; x.f = f;
  unsigned int r = x.u + 0x7fffu + ((x.u >> 16) & 1u);
  return (u16)(r >> 16);
}

// Kernel 0: W1 (1024x128 f32) -> bf16 MFMA B-fragment order (blocks 0..511),
// plus W2 (128x24 f32, zero-padded to 32 cols) -> bf16 B-fragments (block 512).
__global__ __launch_bounds__(256) void k0_w1frag(const float* __restrict__ W1,
                                                 const float* __restrict__ W2,
                                                 u16* __restrict__ w1f,
                                                 u16* __restrict__ w2f) {
  if (blockIdx.x < 512) {
    int idx = blockIdx.x * 256 + threadIdx.x;   // 0..131071
    int k = idx >> 7, c = idx & 127;
    float v = W1[idx];
    int chunk = k >> 6, kk = k & 63;
    int ks = kk >> 5, km = kk & 31, kg = km >> 3, i = km & 7;
    int nt = c >> 4, ln = c & 15;
    int dst = chunk * 8192 + (nt * 2 + ks) * 512 + (kg * 16 + ln) * 8 + i;
    w1f[dst] = f2b(v);
  } else {
    // W2 fragments: (kstep s=0..3, nt=0..1): lane l holds
    // W2[s*32 + 8*(l>>4) + i][nt*16 + (l&15)] (0 if col>=24).
    #pragma unroll
    for (int rep = 0; rep < 2; ++rep) {
      int p = threadIdx.x + rep * 256;   // 0..511
      int f = p >> 6, l = p & 63;
      int s = f >> 1, nt = f & 1;
      int kbase = s * 32 + (l >> 4) * 8;
      int c = nt * 16 + (l & 15);
      u16x8 v;
      #pragma unroll
      for (int i = 0; i < 8; ++i)
        v[i] = (c < 24) ? f2b(W2[(size_t)(kbase + i) * 24 + c]) : (u16)0;
      *(u16x8*)&w2f[f * 512 + l * 8] = v;
    }
  }
}

// Kernel 1: 512 blocks x 16 rows, 256 threads (4 waves), 2 blocks/CU.
// Double-buffered A/W tiles (r11 structure). Bias projection via MFMA on
// wave 0 (replaces the 480-LDS-inst VALU dot product).
// smem: Al[2] @0/2048 | Wl[2] @4096/20480. xt (8448B) aliases @0 post-loop.
__global__ __launch_bounds__(256) void k1_prep(
    const float* __restrict__ inputs, const u16* __restrict__ w1f,
    const u16* __restrict__ w2f, const float* __restrict__ b1,
    const float* __restrict__ b2,
    u16* __restrict__ qw, u16* __restrict__ kw,
    float* __restrict__ biasE, float* __restrict__ biasO) {
  __shared__ __align__(16) char smem[36864];
  float* xt = (float*)smem;             // 16 x 132 f32 (alias, post-loop)

  int t = threadIdx.x;
  int lane = t & 63, w = t >> 6;        // 4 waves
  int r0 = blockIdx.x * 16;
  int b = r0 >> 9, l0 = r0 & 511;

  f32x4 acc[2];
  acc[0] = (f32x4){0.f, 0.f, 0.f, 0.f};
  acc[1] = (f32x4){0.f, 0.f, 0.f, 0.f};

  int wnt = w * 2;

  int arow_s = t >> 4;                   // 0..15
  int aseg = t & 15;
  const float* ain = &inputs[(size_t)(r0 + arow_s) * 1024 + aseg * 4];
  int abyt = (arow_s * 128 + aseg * 8) ^ ((arow_s & 7) << 4);
  const float4* wsrcAll = (const float4*)w1f;

  float4 a0 = *(const float4*)(ain);
  float4 wr0 = wsrcAll[t];
  float4 wr1 = wsrcAll[t + 256];
  float4 wr2 = wsrcAll[t + 512];
  float4 wr3 = wsrcAll[t + 768];
  {
    u16x4 av;
    av[0] = f2b(a0.x); av[1] = f2b(a0.y); av[2] = f2b(a0.z); av[3] = f2b(a0.w);
    *(u16x4*)(smem + abyt) = av;
    float4* wd = (float4*)(smem + 4096);
    wd[t] = wr0; wd[t + 256] = wr1; wd[t + 512] = wr2; wd[t + 768] = wr3;
  }
  __syncthreads();

  for (int ch = 0; ch < 16; ++ch) {
    if (ch < 15) {
      a0 = *(const float4*)(ain + (ch + 1) * 64);
      const float4* wsrc = wsrcAll + (ch + 1) * 1024;
      wr0 = wsrc[t]; wr1 = wsrc[t + 256]; wr2 = wsrc[t + 512]; wr3 = wsrc[t + 768];
    }
    {
      const char* Ab = smem + (ch & 1) * 2048;
      const u16* Wb = (const u16*)(smem + 4096 + (ch & 1) * 16384);
      int arow = lane & 15;
      int hi = lane >> 4;
      #pragma unroll
      for (int ks = 0; ks < 2; ++ks) {
        int cb = ks * 64 + hi * 16;
        bf16x8 a = *(const bf16x8*)(Ab + ((arow * 128 + cb) ^ ((arow & 7) << 4)));
        #pragma unroll
        for (int nti = 0; nti < 2; ++nti) {
          int nt = wnt + nti;
          bf16x8 bb = *(const bf16x8*)&Wb[((nt * 2 + ks) * 64 + lane) * 8];
          acc[nti] = __builtin_amdgcn_mfma_f32_16x16x32_bf16(a, bb, acc[nti], 0, 0, 0);
        }
      }
    }
    if (ch < 15) {
      int q = (ch + 1) & 1;
      u16x4 av;
      av[0] = f2b(a0.x); av[1] = f2b(a0.y); av[2] = f2b(a0.z); av[3] = f2b(a0.w);
      *(u16x4*)(smem + q * 2048 + abyt) = av;
      float4* wd = (float4*)(smem + 4096 + q * 16384);
      wd[t] = wr0; wd[t + 256] = wr1; wd[t + 512] = wr2; wd[t + 768] = wr3;
    }
    __syncthreads();
  }
  __syncthreads();  // all MFMA reads done before xt aliases Al/Wl

  // epilogue: acc -> xt (+ b1). D: col=lane&15, row=(lane>>4)*4+r
  #pragma unroll
  for (int nti = 0; nti < 2; ++nti) {
    int c = (wnt + nti) * 16 + (lane & 15);
    float b1v = b1[c];
    #pragma unroll
    for (int r = 0; r < 4; ++r) {
      int row = ((lane >> 4) << 2) + r;
      xt[row * 132 + c] = acc[nti][r] + b1v;
    }
  }
  __syncthreads();

  // RoPE: thread handles row t>>4, j = (t&15)*2 .. +1 ; outputs bf16
  {
    int r = t >> 4, jb = (t & 15) * 2;
    int l = l0 + r;
    float fl = (float)l;
    u16x4 qv, kv;
    #pragma unroll
    for (int p = 0; p < 2; ++p) {
      int j = jb + p;
      float4 x4 = *(const float4*)&xt[r * 132 + 4 * j];
      float invf = exp2f(-0.4152410118609203f * (float)j);  // 10000^(-j/32)
      float ang = fl * invf;
      float rev = ang * 0.15915494309189535f;
      rev = rev - floorf(rev);
      float sv, cv;
      __sincosf(rev * 6.2831853071795864f, &sv, &cv);
      qv[2 * p] = f2b(x4.x * cv - x4.z * sv);
      qv[2 * p + 1] = f2b(x4.x * sv + x4.z * cv);
      kv[2 * p] = f2b(x4.y * cv - x4.w * sv);
      kv[2 * p + 1] = f2b(x4.y * sv + x4.w * cv);
    }
    size_t base = ((size_t)(b * 512 + l)) * 64 + jb * 2;
    *(u16x4*)&qw[base] = qv;
    *(u16x4*)&kw[base] = kv;
  }

  // bias projection via MFMA (wave 0 only): bias = (x @ W2 + b2)/2.
  // A-frag: lane l holds x[l&15][s*32 + 8*(l>>4) + i] from xt (f32 -> bf16).
  if (w == 0) {
    f32x4 acc2[2];
    acc2[0] = (f32x4){0.f, 0.f, 0.f, 0.f};
    acc2[1] = (f32x4){0.f, 0.f, 0.f, 0.f};
    int r = lane & 15, kg = lane >> 4;
    #pragma unroll
    for (int s = 0; s < 4; ++s) {
      const float* xp = &xt[r * 132 + s * 32 + kg * 8];
      float4 f0 = *(const float4*)xp;
      float4 f1 = *(const float4*)(xp + 4);
      bf16x8 a2;
      a2[0] = (short)f2b(f0.x); a2[1] = (short)f2b(f0.y);
      a2[2] = (short)f2b(f0.z); a2[3] = (short)f2b(f0.w);
      a2[4] = (short)f2b(f1.x); a2[5] = (short)f2b(f1.y);
      a2[6] = (short)f2b(f1.z); a2[7] = (short)f2b(f1.w);
      bf16x8 w20 = *(const bf16x8*)&w2f[(s * 2 + 0) * 512 + lane * 8];
      bf16x8 w21 = *(const bf16x8*)&w2f[(s * 2 + 1) * 512 + lane * 8];
      acc2[0] = __builtin_amdgcn_mfma_f32_16x16x32_bf16(a2, w20, acc2[0], 0, 0, 0);
      acc2[1] = __builtin_amdgcn_mfma_f32_16x16x32_bf16(a2, w21, acc2[1], 0, 0, 0);
    }
    #pragma unroll
    for (int nt = 0; nt < 2; ++nt) {
      int c = nt * 16 + (lane & 15);
      if (c < 24) {
        float b2v = b2[c];
        int h = c >> 1;
        float* dst = (c & 1) ? biasO : biasE;
        size_t base = ((size_t)(b * 12 + h)) * 512 + l0 + ((lane >> 4) << 2);
        #pragma unroll
        for (int r2 = 0; r2 < 4; ++r2)
          dst[base + r2] = (acc2[nt][r2] + b2v) * 0.5f;
      }
    }
  }
}

// Kernel 2: identical to round 11 (measured ~32.3 us, ~store floor).
__global__ __launch_bounds__(256) void k2_main(
    const u16* __restrict__ qw, const u16* __restrict__ kw,
    const float* __restrict__ biasE, const float* __restrict__ biasO,
    const float* __restrict__ amask, float* __restrict__ out) {
  __shared__ char smem[24448];
  u16* Q = (u16*)smem;              // 8KB swizzled [m][d]
  u16* K = (u16*)(smem + 8192);     // 8KB swizzled [n][d]
  float* qkL = (float*)smem;        // 64x68 f32 (17408B) — overlaps Q/K (dead)
  float* BN = (float*)(smem + 17408);
  float* BM = (float*)(smem + 17408 + 3264);
  float* AMm = (float*)(smem + 17408 + 6528);
  float* AMn = AMm + 64;

  int t = threadIdx.x;
  int lane = t & 63, w = t >> 6;
  int n0 = blockIdx.x * 64, m0 = blockIdx.y * 64, b = blockIdx.z;
  bool skip = (m0 >= n0 + 64);  // fully below diagonal

  if (!skip) {
    int row = t >> 2, sg = t & 3;
    const u16x8* qsrc = (const u16x8*)&qw[((size_t)(b * 512 + m0 + row)) * 64 + sg * 16];
    u16x8 q0 = qsrc[0], q1 = qsrc[1];
    const u16x8* ksrc = (const u16x8*)&kw[((size_t)(b * 512 + n0 + row)) * 64 + sg * 16];
    u16x8 k0v = ksrc[0], k1v = ksrc[1];
    int swz = (row & 7) << 4;
    int byt = row * 128 + sg * 32;
    *(u16x8*)((char*)Q + ((byt) ^ swz)) = q0;
    *(u16x8*)((char*)Q + ((byt + 16) ^ swz)) = q1;
    *(u16x8*)((char*)K + ((byt) ^ swz)) = k0v;
    *(u16x8*)((char*)K + ((byt + 16) ^ swz)) = k1v;
  }
  if (t < 192) {
    int h = t >> 4, kq = t & 15;
    *(float4*)&BN[h * 68 + kq * 4] =
        *(const float4*)&biasE[((size_t)(b * 12 + h)) * 512 + n0 + kq * 4];
    *(float4*)&BM[h * 68 + kq * 4] =
        *(const float4*)&biasO[((size_t)(b * 12 + h)) * 512 + m0 + kq * 4];
  } else if (t < 224) {
    int i = t - 192;
    if (i < 16) *(float4*)&AMm[i * 4] = *(const float4*)&amask[b * 512 + m0 + i * 4];
    else { int ii = i - 16; *(float4*)&AMn[ii * 4] = *(const float4*)&amask[b * 512 + n0 + ii * 4]; }
  }
  __syncthreads();

  if (!skip) {
    f32x4 acc[4];
    #pragma unroll
    for (int nt = 0; nt < 4; ++nt) acc[nt] = (f32x4){0.f, 0.f, 0.f, 0.f};
    int mrow = w * 16 + (lane & 15);
    int hi = lane >> 4;
    #pragma unroll
    for (int ks = 0; ks < 2; ++ks) {
      int cb = ks * 64 + hi * 16;
      bf16x8 a = *(const bf16x8*)((const char*)Q +
                                  ((mrow * 128 + cb) ^ ((mrow & 7) << 4)));
      #pragma unroll
      for (int nt = 0; nt < 4; ++nt) {
        int nr = nt * 16 + (lane & 15);
        bf16x8 bb = *(const bf16x8*)((const char*)K +
                                     ((nr * 128 + cb) ^ ((nr & 7) << 4)));
        acc[nt] = __builtin_amdgcn_mfma_f32_16x16x32_bf16(a, bb, acc[nt], 0, 0, 0);
      }
    }
    __syncthreads();  // Q/K dead; safe to overwrite with qkL
    #pragma unroll
    for (int nt = 0; nt < 4; ++nt)
      #pragma unroll
      for (int r = 0; r < 4; ++r)
        qkL[(w * 16 + hi * 4 + r) * 68 + nt * 16 + (lane & 15)] = acc[nt][r];
    __syncthreads();
  }

  int a15 = t & 15, mb = t >> 4;  // thread owns n = 4*a15+j, m = mb+16*mi
  float amn0 = AMn[a15 * 4 + 0], amn1 = AMn[a15 * 4 + 1];
  float amn2 = AMn[a15 * 4 + 2], amn3 = AMn[a15 * 4 + 3];
  float vals[4][4];
  #pragma unroll
  for (int mi = 0; mi < 4; ++mi) {
    int m = mb + 16 * mi;
    int mg = m0 + m;
    float amm = AMm[m];
    int ng = n0 + a15 * 4;
    float p0 = (1.f - amm * amn0) * FINF + ((mg > ng + 0) ? FINF : 0.f);
    float p1 = (1.f - amm * amn1) * FINF + ((mg > ng + 1) ? FINF : 0.f);
    float p2 = (1.f - amm * amn2) * FINF + ((mg > ng + 2) ? FINF : 0.f);
    float p3 = (1.f - amm * amn3) * FINF + ((mg > ng + 3) ? FINF : 0.f);
    if (!skip) {
      float4 qk = *(const float4*)&qkL[m * 68 + a15 * 4];
      vals[mi][0] = qk.x * 0.125f - p0;
      vals[mi][1] = qk.y * 0.125f - p1;
      vals[mi][2] = qk.z * 0.125f - p2;
      vals[mi][3] = qk.w * 0.125f - p3;
    } else {
      vals[mi][0] = -p0; vals[mi][1] = -p1; vals[mi][2] = -p2; vals[mi][3] = -p3;
    }
  }

  size_t outbase = (size_t)(b * 12) * 262144 + (size_t)m0 * 512 + n0 + a15 * 4;
  #pragma unroll
  for (int h = 0; h < 12; ++h) {
    float4 bn = *(const float4*)&BN[h * 68 + a15 * 4];
    #pragma unroll
    for (int mi = 0; mi < 4; ++mi) {
      int m = mb + 16 * mi;
      float bm = BM[h * 68 + m];
      float4 v;
      v.x = vals[mi][0] + bn.x + bm;
      v.y = vals[mi][1] + bn.y + bm;
      v.z = vals[mi][2] + bn.z + bm;
      v.w = vals[mi][3] + bn.w + bm;
      *(float4*)&out[outbase + (size_t)h * 262144 + (size_t)m * 512] = v;
    }
  }
}

extern "C" void kernel_launch(void* const* d_in, const int* in_sizes, int n_in,
                              void* d_out, int out_size, void* d_ws, size_t ws_size,
                              hipStream_t stream) {
  const float* inputs = (const float*)d_in[0];
  const float* amask  = (const float*)d_in[1];
  const float* W1     = (const float*)d_in[2];
  const float* b1     = (const float*)d_in[3];
  const float* W2     = (const float*)d_in[4];
  const float* b2     = (const float*)d_in[5];
  float* out = (float*)d_out;

  char* ws = (char*)d_ws;
  u16* qw      = (u16*)(ws);                            // 1 MB
  u16* kw      = (u16*)(ws + (1u << 20));               // 1 MB
  float* biasE = (float*)(ws + (2u << 20));             // 384 KB
  float* biasO = (float*)(ws + (2u << 20) + 393216u);   // 384 KB
  u16* w1f     = (u16*)(ws + (2u << 20) + 786432u);     // 256 KB
  u16* w2f     = (u16*)(ws + (2u << 20) + 786432u + 262144u);  // 8 KB

  k0_w1frag<<<513, 256, 0, stream>>>(W1, W2, w1f, w2f);
  k1_prep<<<512, 256, 0, stream>>>(inputs, w1f, w2f, b1, b2, qw, kw, biasE, biasO);
  k2_main<<<dim3(8, 8, 16), 256, 0, stream>>>(qw, kw, biasE, biasO, amask, out);
}

// Round 15
// 56.067 us; speedup vs baseline: 1.2374x; 1.0194x over previous
//
#include <hip/hip_runtime.h>
#include <hip/hip_bf16.h>

typedef short bf16x8 __attribute__((ext_vector_type(8)));
typedef float f32x4 __attribute__((ext_vector_type(4)));
typedef unsigned short u16;
typedef unsigned short u16x4 __attribute__((ext_vector_type(4)));
typedef unsigned short u16x8 __attribute__((ext_vector_type(8)));

#define FINF 1.0e12f

__device__ __forceinline__ u16 f2b(float f) {
  union { float f; unsigned int u; } x; x.f = f;
  unsigned int r = x.u + 0x7fffu + ((x.u >> 16) & 1u);
  return (u16)(r >> 16);
}

// Kernel 0 (inverted, coalesced): thread owns 8 CONSECUTIVE w1f elements
// (one 16B store), gathers 8 strided W1 reads (L2-absorbed).
// dst d=t8*8+i: i=d&7, ln=(d>>3)&15, kg=(d>>7)&3, ksnt=(d>>9)&15, chunk=d>>13;
// k = chunk*64 + (ksnt&1)*32 + kg*8 + i ; c = (ksnt>>1)*16 + ln.
__global__ __launch_bounds__(256) void k0_w1frag(const float* __restrict__ W1,
                                                 u16* __restrict__ w1f) {
  int t8 = blockIdx.x * 256 + threadIdx.x;   // 0..16383
  int ln = t8 & 15;
  int kg = (t8 >> 4) & 3;
  int ksnt = (t8 >> 6) & 15;
  int chunk = t8 >> 10;
  int ks = ksnt & 1, nt = ksnt >> 1;
  int kbase = chunk * 64 + ks * 32 + kg * 8;
  int c = nt * 16 + ln;
  u16x8 v;
  #pragma unroll
  for (int i = 0; i < 8; ++i) v[i] = f2b(W1[(size_t)(kbase + i) * 128 + c]);
  *(u16x8*)&w1f[t8 * 8] = v;
}

// Kernel 1: identical to round 11 (best measured): 512 blocks x 16 rows,
// 256 threads (4 waves), 2 blocks/CU, double-buffered A/W tiles.
__global__ __launch_bounds__(256) void k1_prep(
    const float* __restrict__ inputs, const u16* __restrict__ w1f,
    const float* __restrict__ b1, const float* __restrict__ W2,
    const float* __restrict__ b2,
    u16* __restrict__ qw, u16* __restrict__ kw,
    float* __restrict__ biasE, float* __restrict__ biasO) {
  __shared__ __align__(16) char smem[49536];
  float* w2t = (float*)(smem + 36864);  // [c][k] pad 132
  float* xt  = (float*)smem;            // 16 x 132 f32 (alias, post-loop)

  int t = threadIdx.x;
  int lane = t & 63, w = t >> 6;        // 4 waves
  int r0 = blockIdx.x * 16;
  int b = r0 >> 9, l0 = r0 & 511;

  #pragma unroll
  for (int i = 0; i < 12; ++i) {
    int idx = t + i * 256;
    int k = idx / 24, c = idx - k * 24;
    w2t[c * 132 + k] = W2[idx];
  }

  f32x4 acc[2];
  acc[0] = (f32x4){0.f, 0.f, 0.f, 0.f};
  acc[1] = (f32x4){0.f, 0.f, 0.f, 0.f};

  int wnt = w * 2;

  int arow_s = t >> 4;                   // 0..15
  int aseg = t & 15;
  const float* ain = &inputs[(size_t)(r0 + arow_s) * 1024 + aseg * 4];
  int abyt = (arow_s * 128 + aseg * 8) ^ ((arow_s & 7) << 4);
  const float4* wsrcAll = (const float4*)w1f;

  float4 a0 = *(const float4*)(ain);
  float4 wr0 = wsrcAll[t];
  float4 wr1 = wsrcAll[t + 256];
  float4 wr2 = wsrcAll[t + 512];
  float4 wr3 = wsrcAll[t + 768];
  {
    u16x4 av;
    av[0] = f2b(a0.x); av[1] = f2b(a0.y); av[2] = f2b(a0.z); av[3] = f2b(a0.w);
    *(u16x4*)(smem + abyt) = av;
    float4* wd = (float4*)(smem + 4096);
    wd[t] = wr0; wd[t + 256] = wr1; wd[t + 512] = wr2; wd[t + 768] = wr3;
  }
  __syncthreads();

  for (int ch = 0; ch < 16; ++ch) {
    if (ch < 15) {
      a0 = *(const float4*)(ain + (ch + 1) * 64);
      const float4* wsrc = wsrcAll + (ch + 1) * 1024;
      wr0 = wsrc[t]; wr1 = wsrc[t + 256]; wr2 = wsrc[t + 512]; wr3 = wsrc[t + 768];
    }
    {
      const char* Ab = smem + (ch & 1) * 2048;
      const u16* Wb = (const u16*)(smem + 4096 + (ch & 1) * 16384);
      int arow = lane & 15;
      int hi = lane >> 4;
      #pragma unroll
      for (int ks = 0; ks < 2; ++ks) {
        int cb = ks * 64 + hi * 16;
        bf16x8 a = *(const bf16x8*)(Ab + ((arow * 128 + cb) ^ ((arow & 7) << 4)));
        #pragma unroll
        for (int nti = 0; nti < 2; ++nti) {
          int nt = wnt + nti;
          bf16x8 bb = *(const bf16x8*)&Wb[((nt * 2 + ks) * 64 + lane) * 8];
          acc[nti] = __builtin_amdgcn_mfma_f32_16x16x32_bf16(a, bb, acc[nti], 0, 0, 0);
        }
      }
    }
    if (ch < 15) {
      int q = (ch + 1) & 1;
      u16x4 av;
      av[0] = f2b(a0.x); av[1] = f2b(a0.y); av[2] = f2b(a0.z); av[3] = f2b(a0.w);
      *(u16x4*)(smem + q * 2048 + abyt) = av;
      float4* wd = (float4*)(smem + 4096 + q * 16384);
      wd[t] = wr0; wd[t + 256] = wr1; wd[t + 512] = wr2; wd[t + 768] = wr3;
    }
    __syncthreads();
  }
  __syncthreads();

  #pragma unroll
  for (int nti = 0; nti < 2; ++nti) {
    int c = (wnt + nti) * 16 + (lane & 15);
    float b1v = b1[c];
    #pragma unroll
    for (int r = 0; r < 4; ++r) {
      int row = ((lane >> 4) << 2) + r;
      xt[row * 132 + c] = acc[nti][r] + b1v;
    }
  }
  __syncthreads();

  {
    int r = t >> 4, jb = (t & 15) * 2;
    int l = l0 + r;
    float fl = (float)l;
    u16x4 qv, kv;
    #pragma unroll
    for (int p = 0; p < 2; ++p) {
      int j = jb + p;
      float4 x4 = *(const float4*)&xt[r * 132 + 4 * j];
      float invf = exp2f(-0.4152410118609203f * (float)j);  // 10000^(-j/32)
      float ang = fl * invf;
      float rev = ang * 0.15915494309189535f;
      rev = rev - floorf(rev);
      float sv, cv;
      __sincosf(rev * 6.2831853071795864f, &sv, &cv);
      qv[2 * p] = f2b(x4.x * cv - x4.z * sv);
      qv[2 * p + 1] = f2b(x4.x * sv + x4.z * cv);
      kv[2 * p] = f2b(x4.y * cv - x4.w * sv);
      kv[2 * p + 1] = f2b(x4.y * sv + x4.w * cv);
    }
    size_t base = ((size_t)(b * 512 + l)) * 64 + jb * 2;
    *(u16x4*)&qw[base] = qv;
    *(u16x4*)&kw[base] = kv;
  }

  if (t < 192) {
    int c = t >> 3;
    int rg = (t & 7) * 2;
    float s0 = b2[c], s1 = s0;
    #pragma unroll
    for (int k4 = 0; k4 < 32; ++k4) {
      float4 wv = *(const float4*)&w2t[c * 132 + k4 * 4];
      float4 x0 = *(const float4*)&xt[(rg + 0) * 132 + k4 * 4];
      float4 x1 = *(const float4*)&xt[(rg + 1) * 132 + k4 * 4];
      s0 += x0.x * wv.x + x0.y * wv.y + x0.z * wv.z + x0.w * wv.w;
      s1 += x1.x * wv.x + x1.y * wv.y + x1.z * wv.z + x1.w * wv.w;
    }
    int h = c >> 1;
    size_t o = ((size_t)(b * 12 + h)) * 512 + l0 + rg;
    float2 sv = {s0 * 0.5f, s1 * 0.5f};
    if (c & 1) *(float2*)&biasO[o] = sv;
    else       *(float2*)&biasE[o] = sv;
  }
}

// Kernel 2: identical to round 11 (measured ~32.3 us, ~store floor).
__global__ __launch_bounds__(256) void k2_main(
    const u16* __restrict__ qw, const u16* __restrict__ kw,
    const float* __restrict__ biasE, const float* __restrict__ biasO,
    const float* __restrict__ amask, float* __restrict__ out) {
  __shared__ char smem[24448];
  u16* Q = (u16*)smem;              // 8KB swizzled [m][d]
  u16* K = (u16*)(smem + 8192);     // 8KB swizzled [n][d]
  float* qkL = (float*)smem;        // 64x68 f32 (17408B) — overlaps Q/K (dead)
  float* BN = (float*)(smem + 17408);
  float* BM = (float*)(smem + 17408 + 3264);
  float* AMm = (float*)(smem + 17408 + 6528);
  float* AMn = AMm + 64;

  int t = threadIdx.x;
  int lane = t & 63, w = t >> 6;
  int n0 = blockIdx.x * 64, m0 = blockIdx.y * 64, b = blockIdx.z;
  bool skip = (m0 >= n0 + 64);  // fully below diagonal

  if (!skip) {
    int row = t >> 2, sg = t & 3;
    const u16x8* qsrc = (const u16x8*)&qw[((size_t)(b * 512 + m0 + row)) * 64 + sg * 16];
    u16x8 q0 = qsrc[0], q1 = qsrc[1];
    const u16x8* ksrc = (const u16x8*)&kw[((size_t)(b * 512 + n0 + row)) * 64 + sg * 16];
    u16x8 k0v = ksrc[0], k1v = ksrc[1];
    int swz = (row & 7) << 4;
    int byt = row * 128 + sg * 32;
    *(u16x8*)((char*)Q + ((byt) ^ swz)) = q0;
    *(u16x8*)((char*)Q + ((byt + 16) ^ swz)) = q1;
    *(u16x8*)((char*)K + ((byt) ^ swz)) = k0v;
    *(u16x8*)((char*)K + ((byt + 16) ^ swz)) = k1v;
  }
  if (t < 192) {
    int h = t >> 4, kq = t & 15;
    *(float4*)&BN[h * 68 + kq * 4] =
        *(const float4*)&biasE[((size_t)(b * 12 + h)) * 512 + n0 + kq * 4];
    *(float4*)&BM[h * 68 + kq * 4] =
        *(const float4*)&biasO[((size_t)(b * 12 + h)) * 512 + m0 + kq * 4];
  } else if (t < 224) {
    int i = t - 192;
    if (i < 16) *(float4*)&AMm[i * 4] = *(const float4*)&amask[b * 512 + m0 + i * 4];
    else { int ii = i - 16; *(float4*)&AMn[ii * 4] = *(const float4*)&amask[b * 512 + n0 + ii * 4]; }
  }
  __syncthreads();

  if (!skip) {
    f32x4 acc[4];
    #pragma unroll
    for (int nt = 0; nt < 4; ++nt) acc[nt] = (f32x4){0.f, 0.f, 0.f, 0.f};
    int mrow = w * 16 + (lane & 15);
    int hi = lane >> 4;
    #pragma unroll
    for (int ks = 0; ks < 2; ++ks) {
      int cb = ks * 64 + hi * 16;
      bf16x8 a = *(const bf16x8*)((const char*)Q +
                                  ((mrow * 128 + cb) ^ ((mrow & 7) << 4)));
      #pragma unroll
      for (int nt = 0; nt < 4; ++nt) {
        int nr = nt * 16 + (lane & 15);
        bf16x8 bb = *(const bf16x8*)((const char*)K +
                                     ((nr * 128 + cb) ^ ((nr & 7) << 4)));
        acc[nt] = __builtin_amdgcn_mfma_f32_16x16x32_bf16(a, bb, acc[nt], 0, 0, 0);
      }
    }
    __syncthreads();  // Q/K dead; safe to overwrite with qkL
    #pragma unroll
    for (int nt = 0; nt < 4; ++nt)
      #pragma unroll
      for (int r = 0; r < 4; ++r)
        qkL[(w * 16 + hi * 4 + r) * 68 + nt * 16 + (lane & 15)] = acc[nt][r];
    __syncthreads();
  }

  int a15 = t & 15, mb = t >> 4;  // thread owns n = 4*a15+j, m = mb+16*mi
  float amn0 = AMn[a15 * 4 + 0], amn1 = AMn[a15 * 4 + 1];
  float amn2 = AMn[a15 * 4 + 2], amn3 = AMn[a15 * 4 + 3];
  float vals[4][4];
  #pragma unroll
  for (int mi = 0; mi < 4; ++mi) {
    int m = mb + 16 * mi;
    int mg = m0 + m;
    float amm = AMm[m];
    int ng = n0 + a15 * 4;
    float p0 = (1.f - amm * amn0) * FINF + ((mg > ng + 0) ? FINF : 0.f);
    float p1 = (1.f - amm * amn1) * FINF + ((mg > ng + 1) ? FINF : 0.f);
    float p2 = (1.f - amm * amn2) * FINF + ((mg > ng + 2) ? FINF : 0.f);
    float p3 = (1.f - amm * amn3) * FINF + ((mg > ng + 3) ? FINF : 0.f);
    if (!skip) {
      float4 qk = *(const float4*)&qkL[m * 68 + a15 * 4];
      vals[mi][0] = qk.x * 0.125f - p0;
      vals[mi][1] = qk.y * 0.125f - p1;
      vals[mi][2] = qk.z * 0.125f - p2;
      vals[mi][3] = qk.w * 0.125f - p3;
    } else {
      vals[mi][0] = -p0; vals[mi][1] = -p1; vals[mi][2] = -p2; vals[mi][3] = -p3;
    }
  }

  size_t outbase = (size_t)(b * 12) * 262144 + (size_t)m0 * 512 + n0 + a15 * 4;
  #pragma unroll
  for (int h = 0; h < 12; ++h) {
    float4 bn = *(const float4*)&BN[h * 68 + a15 * 4];
    #pragma unroll
    for (int mi = 0; mi < 4; ++mi) {
      int m = mb + 16 * mi;
      float bm = BM[h * 68 + m];
      float4 v;
      v.x = vals[mi][0] + bn.x + bm;
      v.y = vals[mi][1] + bn.y + bm;
      v.z = vals[mi][2] + bn.z + bm;
      v.w = vals[mi][3] + bn.w + bm;
      *(float4*)&out[outbase + (size_t)h * 262144 + (size_t)m * 512] = v;
    }
  }
}

extern "C" void kernel_launch(void* const* d_in, const int* in_sizes, int n_in,
                              void* d_out, int out_size, void* d_ws, size_t ws_size,
                              hipStream_t stream) {
  const float* inputs = (const float*)d_in[0];
  const float* amask  = (const float*)d_in[1];
  const float* W1     = (const float*)d_in[2];
  const float* b1     = (const float*)d_in[3];
  const float* W2     = (const float*)d_in[4];
  const float* b2     = (const float*)d_in[5];
  float* out = (float*)d_out;

  char* ws = (char*)d_ws;
  u16* qw      = (u16*)(ws);                            // 1 MB
  u16* kw      = (u16*)(ws + (1u << 20));               // 1 MB
  float* biasE = (float*)(ws + (2u << 20));             // 384 KB
  float* biasO = (float*)(ws + (2u << 20) + 393216u);   // 384 KB
  u16* w1f     = (u16*)(ws + (2u << 20) + 786432u);     // 256 KB

  k0_w1frag<<<64, 256, 0, stream>>>(W1, w1f);
  k1_prep<<<512, 256, 0, stream>>>(inputs, w1f, b1, W2, b2, qw, kw, biasE, biasO);
  k2_main<<<dim3(8, 8, 16), 256, 0, stream>>>(qw, kw, biasE, biasO, amask, out);
}